// Round 1
// baseline (243.331 us; speedup 1.0000x reference)
//
#include <hip/hip_runtime.h>

// Problem constants (from reference)
#define NUM_BLOCKS 1024
#define BLOCK_SIZE 128
#define NUM_HEADS 8
#define HEAD_DIM 128
#define NUM_TOKENS 8192
#define ROW_FLOATS (NUM_HEADS * HEAD_DIM)        // 1024 floats per slot row
#define ROW_F4 (ROW_FLOATS / 4)                  // 256 float4 per slot row
#define TOTAL_F4 ((size_t)NUM_BLOCKS * BLOCK_SIZE * ROW_F4)  // 33,554,432 float4

// Kernel 1: vectorized full-cache copy, grid-stride over float4s.
__global__ void kv_copy_cache(const float4* __restrict__ src,
                              float4* __restrict__ dst) {
    size_t i = (size_t)blockIdx.x * blockDim.x + threadIdx.x;
    const size_t stride = (size_t)gridDim.x * blockDim.x;
    for (; i < TOTAL_F4; i += stride) {
        dst[i] = src[i];
    }
}

// Kernel 2: one block per token; 256 threads each move one float4 of the
// token's 1024-float row into its destination slot.
__global__ void kv_scatter_tokens(const float4* __restrict__ inp,
                                  const int* __restrict__ bidx,
                                  const int* __restrict__ boff,
                                  float4* __restrict__ out) {
    const int tok = blockIdx.x;       // 0..NUM_TOKENS-1
    const int c = threadIdx.x;        // 0..255
    const long slot = (long)bidx[tok] * BLOCK_SIZE + (long)boff[tok];
    out[slot * ROW_F4 + c] = inp[(size_t)tok * ROW_F4 + c];
}

extern "C" void kernel_launch(void* const* d_in, const int* in_sizes, int n_in,
                              void* d_out, int out_size, void* d_ws, size_t ws_size,
                              hipStream_t stream) {
    const float* input = (const float*)d_in[0];        // [8192, 8, 128] fp32
    const float* cache = (const float*)d_in[1];        // [1024, 128, 8, 128] fp32
    const int* block_indices = (const int*)d_in[2];    // [8192] int
    const int* block_offset = (const int*)d_in[3];     // [8192] int
    float* out = (float*)d_out;                        // [1024, 128, 8, 128] fp32

    // 1) copy cache -> out  (512 MiB read + 512 MiB write)
    kv_copy_cache<<<2048, 256, 0, stream>>>((const float4*)cache, (float4*)out);

    // 2) scatter input rows into out (stream-ordered after the copy)
    kv_scatter_tokens<<<NUM_TOKENS, 256, 0, stream>>>(
        (const float4*)input, block_indices, block_offset, (float4*)out);
}

// Round 3
// 179.580 us; speedup vs baseline: 1.3550x; 1.3550x over previous
//
#include <hip/hip_runtime.h>

// Problem constants (from reference)
#define NUM_BLOCKS 1024
#define BLOCK_SIZE 128
#define NUM_HEADS 8
#define HEAD_DIM 128
#define NUM_TOKENS 8192
#define ROW_FLOATS (NUM_HEADS * HEAD_DIM)        // 1024 floats per slot row
#define ROW_F4 (ROW_FLOATS / 4)                  // 256 float4 per slot row
#define TOTAL_ROWS (NUM_BLOCKS * BLOCK_SIZE)     // 131072 slot rows

typedef float f32x4 __attribute__((ext_vector_type(4)));  // native vec for nontemporal builtins

// Kernel 1: init slot->token map to -1.
__global__ void kv_map_init(int* __restrict__ map) {
    const int i = blockIdx.x * blockDim.x + threadIdx.x;
    map[i] = -1;
}

// Kernel 2: scatter token ids into the map (destination slots are unique).
__global__ void kv_map_scatter(const int* __restrict__ bidx,
                               const int* __restrict__ boff,
                               int* __restrict__ map) {
    const int t = blockIdx.x * blockDim.x + threadIdx.x;
    if (t < NUM_TOKENS) {
        map[bidx[t] * BLOCK_SIZE + boff[t]] = t;
    }
}

// Kernel 3: output-driven fused copy. One wave per slot row; 4 rows per block.
// Each row is 1024 floats = 256 f32x4; each of the 64 lanes moves 4 f32x4.
__global__ void kv_fused_copy(const f32x4* __restrict__ inp,
                              const f32x4* __restrict__ cache,
                              const int* __restrict__ map,
                              f32x4* __restrict__ out) {
    const int row  = blockIdx.x * 4 + (threadIdx.x >> 6);   // slot row
    const int lane = threadIdx.x & 63;
    const int tok  = map[row];                               // wave-uniform
    const f32x4* __restrict__ src =
        (tok >= 0) ? (inp + (size_t)tok * ROW_F4)
                   : (cache + (size_t)row * ROW_F4);
    f32x4* __restrict__ dst = out + (size_t)row * ROW_F4;
#pragma unroll
    for (int i = 0; i < 4; ++i) {
        f32x4 v = __builtin_nontemporal_load(&src[lane + 64 * i]);
        __builtin_nontemporal_store(v, &dst[lane + 64 * i]);
    }
}

extern "C" void kernel_launch(void* const* d_in, const int* in_sizes, int n_in,
                              void* d_out, int out_size, void* d_ws, size_t ws_size,
                              hipStream_t stream) {
    const float* input = (const float*)d_in[0];        // [8192, 8, 128] fp32
    const float* cache = (const float*)d_in[1];        // [1024, 128, 8, 128] fp32
    const int* block_indices = (const int*)d_in[2];    // [8192] int
    const int* block_offset = (const int*)d_in[3];     // [8192] int
    float* out = (float*)d_out;                        // [1024, 128, 8, 128] fp32
    int* map = (int*)d_ws;                             // 131072 ints (512 KiB)

    kv_map_init<<<TOTAL_ROWS / 256, 256, 0, stream>>>(map);
    kv_map_scatter<<<NUM_TOKENS / 256, 256, 0, stream>>>(block_indices,
                                                         block_offset, map);
    kv_fused_copy<<<TOTAL_ROWS / 4, 256, 0, stream>>>(
        (const f32x4*)input, (const f32x4*)cache, map, (f32x4*)out);
}